// Round 12
// baseline (84.195 us; speedup 1.0000x reference)
//
#include <hip/hip_runtime.h>
#include <hip/hip_bf16.h>

typedef __attribute__((ext_vector_type(8))) short short8;
typedef __attribute__((ext_vector_type(4))) float f32x4;
typedef unsigned int u32;

#define LDSW 136  // padded row stride (bf16 elems) = 272 B

// round-to-nearest-even f32 -> bf16
static __device__ __forceinline__ ushort f2bf(float f) {
  unsigned int u = __builtin_bit_cast(unsigned int, f);
  u += 0x7fffu + ((u >> 16) & 1u);
  return (ushort)(u >> 16);
}

// ---------------- kernel 1: pack w1 (f32 row-major) -> bf16 [col][k] with padded stride ----
__global__ __launch_bounds__(256) void pack_w1_kernel(const float* __restrict__ w1,
                                                      ushort* __restrict__ w1p) {
  int tid = blockIdx.x * 256 + threadIdx.x;
  int k = tid >> 7;
  int c = tid & 127;
  w1p[c * LDSW + k] = f2bf(w1[k * 128 + c]);
}

// ---------------- kernel 2: column-sum with NONTEMPORAL loads ------------------------------
// R11 audit: rocprof per-kernel durations are inflated (R1: transmit 69 + colsum 62 + gemm
// >=15 > total 137); only dur_us deltas are trustworthy. Untried causal lever: all prior
// reads ALLOCATE in L2 — streaming 102MB through 4MB/XCD L2s churns allocate/evict on the
// read path. NT loads (no-allocate) bypass the churn. Same tile/partial layout as R10
// (bitwise-identical partials: thread tid sums rows {tid>>5, 8+tid>>5, ..., 56+tid>>5} at
// float4-col tid&31 of its block's 64-row tile).
__global__ __launch_bounds__(256) void colsum_nt_kernel(const float* __restrict__ x,
                                                        float4* __restrict__ partial4) {
  __shared__ float red[8][32][4];
  int tid = threadIdx.x;
  const f32x4* bb = reinterpret_cast<const f32x4*>(x) + (size_t)blockIdx.x * 2048;

  f32x4 v[8];
#pragma unroll
  for (int k = 0; k < 8; ++k) v[k] = __builtin_nontemporal_load(&bb[k * 256 + tid]);
  f32x4 acc = v[0];
#pragma unroll
  for (int k = 1; k < 8; ++k) acc += v[k];

  int rg = tid >> 5;
  int c4 = tid & 31;
#pragma unroll
  for (int j = 0; j < 4; ++j) red[rg][c4][j] = acc[j];
  __syncthreads();
  if (tid < 32) {
    f32x4 s;
#pragma unroll
    for (int j = 0; j < 4; ++j) s[j] = red[0][tid][j];
#pragma unroll
    for (int g = 1; g < 8; ++g) {
#pragma unroll
      for (int j = 0; j < 4; ++j) s[j] += red[g][tid][j];
    }
    float4 o = {s[0], s[1], s[2], s[3]};
    partial4[(size_t)blockIdx.x * 32 + tid] = o;
  }
}

// ---------------- kernel 3: reduce partial[3125][128] -> partial2[128][128] ----------------
__global__ __launch_bounds__(256) void reduce_kernel(const float* __restrict__ partial,
                                                     float* __restrict__ partial2,
                                                     int nb) {
  int tid = threadIdx.x;
  int j = tid & 127;
  int orow = blockIdx.x * 2 + (tid >> 7);  // 64 blocks -> orow 0..127
  float s = 0.f;
  for (int r = orow; r < nb; r += 128) s += partial[(size_t)r * 128 + j];
  partial2[orow * 128 + j] = s;
}

// ---------------- kernel 4: t = (pooled @ w2)/n + bias  (1 block x 1024 thr) ---------------
__global__ __launch_bounds__(1024) void transmit_kernel(const float* __restrict__ partial,
                                                        const float* __restrict__ w2,
                                                        const float* __restrict__ bias,
                                                        float* __restrict__ t, int n,
                                                        int nblocks) {
  __shared__ float red[8][128];
  __shared__ float pooled[128];
  int tid = threadIdx.x;
  int j = tid & 127;
  int g = tid >> 7;

  float s = 0.f;
  for (int b = g; b < nblocks; b += 8) s += partial[b * 128 + j];
  red[g][j] = s;
  __syncthreads();
  if (tid < 128) {
    float p = 0.f;
#pragma unroll
    for (int gg = 0; gg < 8; ++gg) p += red[gg][j];
    pooled[j] = p;
  }
  __syncthreads();

  float acc = 0.f;
#pragma unroll
  for (int ii = 0; ii < 16; ++ii) {
    int i = g * 16 + ii;
    acc += pooled[i] * w2[i * 128 + j];
  }
  __syncthreads();
  red[g][j] = acc;
  __syncthreads();
  if (tid < 128) {
    float a = 0.f;
#pragma unroll
    for (int gg = 0; gg < 8; ++gg) a += red[gg][j];
    t[j] = a / (float)n + bias[j];
  }
}

// ---------------- kernel 5: out = x @ w1 + t  (bf16 MFMA; NT x-loads, plain stores) --------
__global__ __launch_bounds__(256) void gemm_kernel(const float* __restrict__ x,
                                                   const ushort* __restrict__ w1p,
                                                   const float* __restrict__ tvec,
                                                   float* __restrict__ out) {
  __shared__ ushort w1t[128 * LDSW];
  __shared__ float t_lds[128];
  int tid = threadIdx.x;

  {
    const ulonglong2* src = reinterpret_cast<const ulonglong2*>(w1p);
    ulonglong2* dst = reinterpret_cast<ulonglong2*>(w1t);
#pragma unroll
    for (int i = 0; i < (128 * LDSW * 2) / 16 / 256 + 1; ++i) {
      int idx = tid + i * 256;
      if (idx < (128 * LDSW * 2) / 16) dst[idx] = src[idx];
    }
  }
  if (tid < 128) t_lds[tid] = tvec[tid];
  __syncthreads();

  int lane = tid & 63;
  int wave = tid >> 6;
  int c = lane & 15;    // A row-in-tile / B col / D col
  int kg = lane >> 4;   // k-group 0..3
  int rbase = blockIdx.x * 64 + wave * 16;
  const float* xrow = x + (size_t)(rbase + c) * 128;

  f32x4 acc[8];
#pragma unroll
  for (int nb = 0; nb < 8; ++nb) acc[nb] = (f32x4){0.f, 0.f, 0.f, 0.f};

#pragma unroll
  for (int kb = 0; kb < 4; ++kb) {
    int k0 = kb * 32 + kg * 8;
    f32x4 a0 = __builtin_nontemporal_load(reinterpret_cast<const f32x4*>(xrow + k0));
    f32x4 a1 = __builtin_nontemporal_load(reinterpret_cast<const f32x4*>(xrow + k0 + 4));
    short8 afrag;
    afrag[0] = (short)f2bf(a0[0]);
    afrag[1] = (short)f2bf(a0[1]);
    afrag[2] = (short)f2bf(a0[2]);
    afrag[3] = (short)f2bf(a0[3]);
    afrag[4] = (short)f2bf(a1[0]);
    afrag[5] = (short)f2bf(a1[1]);
    afrag[6] = (short)f2bf(a1[2]);
    afrag[7] = (short)f2bf(a1[3]);
#pragma unroll
    for (int nb = 0; nb < 8; ++nb) {
      short8 bfrag = *reinterpret_cast<const short8*>(&w1t[(nb * 16 + c) * LDSW + k0]);
      acc[nb] = __builtin_amdgcn_mfma_f32_16x16x32_bf16(afrag, bfrag, acc[nb], 0, 0, 0);
    }
  }

  // D layout (m89-verified): col = lane&15, row = (lane>>4)*4 + reg; plain stores (R11
  // showed NT stores cost +5.6us)
#pragma unroll
  for (int nb = 0; nb < 8; ++nb) {
    int col = nb * 16 + c;
    float tv = t_lds[col];
#pragma unroll
    for (int i = 0; i < 4; ++i) {
      out[(size_t)(rbase + kg * 4 + i) * 128 + col] = acc[nb][i] + tv;
    }
  }
}

extern "C" void kernel_launch(void* const* d_in, const int* in_sizes, int n_in,
                              void* d_out, int out_size, void* d_ws, size_t ws_size,
                              hipStream_t stream) {
  const float* x = (const float*)d_in[0];
  const float* w1 = (const float*)d_in[1];
  const float* w2 = (const float*)d_in[2];
  const float* bias = (const float*)d_in[3];
  float* out = (float*)d_out;
  int n = in_sizes[0] / 128;  // 200000
  int nb = n / 64;            // 3125 tile blocks

  char* ws = (char*)d_ws;
  float* t = (float*)ws;                     // 512 B
  ushort* w1p = (ushort*)(ws + 512);         // 34,816 B -> ends 35,328
  float* partial = (float*)(ws + 35328);     // 3125*128*4 = 1,600,000 B -> ends 1,635,328
  float* partial2 = (float*)(ws + 1635328);  // 128*128*4 = 65,536 B

  hipLaunchKernelGGL(pack_w1_kernel, dim3(64), dim3(256), 0, stream, w1, w1p);
  hipLaunchKernelGGL(colsum_nt_kernel, dim3(nb), dim3(256), 0, stream,
                     x, (float4*)partial);
  hipLaunchKernelGGL(reduce_kernel, dim3(64), dim3(256), 0, stream, partial, partial2, nb);
  hipLaunchKernelGGL(transmit_kernel, dim3(1), dim3(1024), 0, stream,
                     partial2, w2, bias, t, n, 128);
  hipLaunchKernelGGL(gemm_kernel, dim3(nb), dim3(256), 0, stream, x, w1p, t, out);
}